// Round 4
// baseline (143.784 us; speedup 1.0000x reference)
//
#include <hip/hip_runtime.h>
#include <cstddef>

// Problem constants:
//   x      [4, 256, 64, 64] fp32
//   offset [4, 18, 64, 64]  fp32   (dy,dx) per 3x3 tap
//   weight [256, 256, 3, 3] fp32
//   out    [4, 256, 64, 64] fp32
// stride=1, pad=1, dil=1 -> Ho=Wo=64
#define B_    4
#define C_    256
#define H_    64
#define W_    64
#define CO_   256
#define K2_   9
#define NSTEP 72      // K = 9*256 = 2304 = 72 steps of 32

typedef __attribute__((ext_vector_type(8))) short short8;
typedef __attribute__((ext_vector_type(4))) float f32x4;

__device__ __forceinline__ unsigned short f2bf(float f) {
    unsigned int u = __builtin_bit_cast(unsigned int, f);
    u = (u + 0x7fffu + ((u >> 16) & 1u)) >> 16;   // RNE
    return (unsigned short)u;
}

__device__ __forceinline__ unsigned pack2bf(float lo, float hi) {
    return (unsigned)f2bf(lo) | ((unsigned)f2bf(hi) << 16);
}

// ---------------------------------------------------------------------------
// weight [Co][C][9] fp32 -> wpk[s][mt][lane][e] bf16 in MFMA A-fragment order.
// A(i,k): i = lane&15 (row within 16-tile), k = 8*(lane>>4)+e.
// c = (s&7)*32 + k, tap = s>>3, o = mt*16 + (lane&15).
// ---------------------------------------------------------------------------
__global__ void wpack_kernel(const float* __restrict__ w,
                             unsigned short* __restrict__ wpk) {
    const int idx = blockIdx.x * 256 + threadIdx.x;   // 72*16*64 = 73728
    if (idx >= NSTEP * 16 * 64) return;
    const int lane = idx & 63;
    const int mt   = (idx >> 6) & 15;
    const int s    = idx >> 10;
    const int o    = mt * 16 + (lane & 15);
    const int kk0  = (lane >> 4) << 3;
    const int tap  = s >> 3;
    const int c0   = (s & 7) << 5;
    unsigned short h[8];
#pragma unroll
    for (int e = 0; e < 8; ++e)
        h[e] = f2bf(w[(o * C_ + c0 + kk0 + e) * K2_ + tap]);
    uint4 v;
    v.x = h[0] | ((unsigned)h[1] << 16);
    v.y = h[2] | ((unsigned)h[3] << 16);
    v.z = h[4] | ((unsigned)h[5] << 16);
    v.w = h[6] | ((unsigned)h[7] << 16);
    *reinterpret_cast<uint4*>(&wpk[(size_t)idx * 8]) = v;
}

__device__ __forceinline__ short8 loadA(const unsigned short* __restrict__ wpk,
                                        const float* __restrict__ wraw,
                                        int use_pk, int s, int mt, int lane) {
    if (use_pk) {
        return *reinterpret_cast<const short8*>(
            wpk + (((size_t)(s * 16 + mt) * 64 + lane) << 3));
    } else {
        const int tap = s >> 3;
        const int cb  = ((s & 7) << 5) + ((lane >> 4) << 3);
        const int o   = mt * 16 + (lane & 15);
        short8 r;
#pragma unroll
        for (int e = 0; e < 8; ++e)
            r[e] = (short)f2bf(wraw[(o * C_ + cb + e) * K2_ + tap]);
        return r;
    }
}

// ---------------------------------------------------------------------------
// Fused deformable conv, bf16 MFMA implicit GEMM, 2-step pipelined.
// Block = (b, ho, wo-half): M=256 x N=32, K=2304. Grid 512 -> 2 blocks/CU.
// 8 waves; wave w owns M rows [32w,32w+32) (2 M-tiles) x 2 N-tiles.
// ---------------------------------------------------------------------------
__global__ __launch_bounds__(512, 4)
void dcn_mfma_kernel(const float* __restrict__ x,
                     const float* __restrict__ off,
                     const unsigned short* __restrict__ wpk,
                     const float* __restrict__ wraw,
                     float* __restrict__ out,
                     int use_pk) {
    __shared__ float s_w[4][K2_][32];      // corner weights (validity folded)
    __shared__ int   s_idx[4][K2_][32];    // clamped plane BYTE offsets
    __shared__ __align__(16) unsigned short s_colb[2][1024]; // [buf][nt*512+l*8+e]

    const int tid = threadIdx.x;
    const int bid = blockIdx.x;
    // XCD swizzle: xcd = bid&7 owns (b = xcd>>1, ho band = (xcd&1)*32).
    // slot in [0,64): ho-in-band = slot>>1, wo-half = slot&1.
    const int xcd  = bid & 7;
    const int slot = bid >> 3;
    const int b    = xcd >> 1;
    const int ho   = ((xcd & 1) << 5) | (slot >> 1);
    const int woh  = slot & 1;             // 0 or 1: wo in [32*woh, 32*woh+32)

    // ---- Phase 1: sampling metadata for 9 taps x 32 wo ---------------------
    if (tid < K2_ * 32) {
        const int k = tid >> 5;
        const int p = tid & 31;
        const int pa = (woh << 5) | p;     // absolute wo
        const float dy = off[((b * 18 + 2 * k    ) * 64 + ho) * 64 + pa];
        const float dx = off[((b * 18 + 2 * k + 1) * 64 + ho) * 64 + pa];
        const float py = (float)(ho - 1 + k / 3) + dy;
        const float px = (float)(pa - 1 + k % 3) + dx;
        const float y0f = floorf(py);
        const float x0f = floorf(px);
        const float ly = py - y0f, lx = px - x0f;
        const float hy = 1.0f - ly, hx = 1.0f - lx;
        const int y0 = (int)y0f, x0 = (int)x0f;
        const int y1 = y0 + 1,   x1 = x0 + 1;
        const bool vy0 = (y0 >= 0) & (y0 < H_);
        const bool vy1 = (y1 >= 0) & (y1 < H_);
        const bool vx0 = (x0 >= 0) & (x0 < W_);
        const bool vx1 = (x1 >= 0) & (x1 < W_);
        const int yc0 = min(max(y0, 0), H_ - 1);
        const int yc1 = min(max(y1, 0), H_ - 1);
        const int xc0 = min(max(x0, 0), W_ - 1);
        const int xc1 = min(max(x1, 0), W_ - 1);
        s_w[0][k][p] = (vy0 && vx0) ? hy * hx : 0.0f;
        s_w[1][k][p] = (vy0 && vx1) ? hy * lx : 0.0f;
        s_w[2][k][p] = (vy1 && vx0) ? ly * hx : 0.0f;
        s_w[3][k][p] = (vy1 && vx1) ? ly * lx : 0.0f;
        s_idx[0][k][p] = (yc0 * W_ + xc0) << 2;
        s_idx[1][k][p] = (yc0 * W_ + xc1) << 2;
        s_idx[2][k][p] = (yc1 * W_ + xc0) << 2;
        s_idx[3][k][p] = (yc1 * W_ + xc1) << 2;
    }
    __syncthreads();

    const int lane = tid & 63;
    const int wave = tid >> 6;
    const int wo   = lane & 31;                        // block-local wo
    const int kk0  = (wave << 2) | ((lane >> 5) << 1); // even, thread stages kk0,kk0+1
    // LDS staging byte offset: nt*1024 + l*16 + e*2, l=(wo&15)+16*(kk0>>3), e=kk0&7
    const unsigned swr = ((unsigned)(wo >> 4) << 10)
                       | ((unsigned)((wo & 15) | ((kk0 >> 3) << 4)) << 4)
                       | ((unsigned)(kk0 & 7) << 1);
    const unsigned brd = (unsigned)lane << 4;          // b-frag read byte offset

    const char* xb8 = (const char*)(x + ((size_t)b * C_ * H_ * W_));

    f32x4 acc[2][2];
#pragma unroll
    for (int m = 0; m < 2; ++m)
#pragma unroll
        for (int nt = 0; nt < 2; ++nt)
            acc[m][nt] = (f32x4)(0.0f);

    // gather-issue: 8 scattered loads (2 planes x 4 corners) for step sN
#define ISSUE(sN, g, wg) do {                                              \
        const int tap_ = (sN) >> 3;                                        \
        const char* pl0_ = xb8 + ((size_t)((((sN) & 7) << 5) + kk0) << 14);\
        const char* pl1_ = pl0_ + (1 << 14);                               \
        const int i0_ = s_idx[0][tap_][wo], i1_ = s_idx[1][tap_][wo];      \
        const int i2_ = s_idx[2][tap_][wo], i3_ = s_idx[3][tap_][wo];      \
        wg[0] = s_w[0][tap_][wo]; wg[1] = s_w[1][tap_][wo];                \
        wg[2] = s_w[2][tap_][wo]; wg[3] = s_w[3][tap_][wo];                \
        g[0] = *(const float*)(pl0_ + i0_); g[1] = *(const float*)(pl0_ + i1_); \
        g[2] = *(const float*)(pl0_ + i2_); g[3] = *(const float*)(pl0_ + i3_); \
        g[4] = *(const float*)(pl1_ + i0_); g[5] = *(const float*)(pl1_ + i1_); \
        g[6] = *(const float*)(pl1_ + i2_); g[7] = *(const float*)(pl1_ + i3_); \
    } while (0)

#define CONVWRITE(buf, g, wg) do {                                         \
        const float v0_ = wg[0]*g[0] + wg[1]*g[1] + wg[2]*g[2] + wg[3]*g[3]; \
        const float v1_ = wg[0]*g[4] + wg[1]*g[5] + wg[2]*g[6] + wg[3]*g[7]; \
        *(unsigned*)((char*)s_colb[buf] + swr) = pack2bf(v0_, v1_);        \
    } while (0)

#define GEMMSTEP(a0, a1, buf) do {                                         \
        short8 b0_ = *(const short8*)((const char*)s_colb[buf] + brd);     \
        short8 b1_ = *(const short8*)((const char*)s_colb[buf] + brd + 1024); \
        acc[0][0] = __builtin_amdgcn_mfma_f32_16x16x32_bf16(a0, b0_, acc[0][0], 0, 0, 0); \
        acc[0][1] = __builtin_amdgcn_mfma_f32_16x16x32_bf16(a0, b1_, acc[0][1], 0, 0, 0); \
        acc[1][0] = __builtin_amdgcn_mfma_f32_16x16x32_bf16(a1, b0_, acc[1][0], 0, 0, 0); \
        acc[1][1] = __builtin_amdgcn_mfma_f32_16x16x32_bf16(a1, b1_, acc[1][1], 0, 0, 0); \
    } while (0)

#define BAR() do {                                                         \
        asm volatile("s_waitcnt lgkmcnt(0)" ::: "memory");                 \
        __builtin_amdgcn_s_barrier();                                      \
    } while (0)

    const int mt0 = wave << 1;
    float gA[8], gB[8], wA[4], wB[4];
    short8 aC0, aC1, aN0, aN1;

    // ---- Prologue: col(0) -> buf0; issue gathers(1); A(0) ------------------
    ISSUE(0, gB, wB);
    aC0 = loadA(wpk, wraw, use_pk, 0, mt0, lane);
    aC1 = loadA(wpk, wraw, use_pk, 0, mt0 + 1, lane);
    CONVWRITE(0, gB, wB);              // vmcnt wait on gB only
    ISSUE(1, gA, wA);                  // in flight across barrier
    BAR();

    // ---- Main loop: 2-step pipelined, unrolled x2 ---------------------------
    for (int s = 0; s < NSTEP; s += 2) {
        // even step: compute col(s) from buf0
        aN0 = loadA(wpk, wraw, use_pk, s + 1, mt0, lane);
        aN1 = loadA(wpk, wraw, use_pk, s + 1, mt0 + 1, lane);
        if (s + 2 < NSTEP) ISSUE(s + 2, gB, wB);
        GEMMSTEP(aC0, aC1, 0);
        CONVWRITE(1, gA, wA);          // col(s+1) -> buf1
        BAR();

        // odd step: compute col(s+1) from buf1
        if (s + 2 < NSTEP) {
            aC0 = loadA(wpk, wraw, use_pk, s + 2, mt0, lane);
            aC1 = loadA(wpk, wraw, use_pk, s + 2, mt0 + 1, lane);
        }
        if (s + 3 < NSTEP) ISSUE(s + 3, gA, wA);
        GEMMSTEP(aN0, aN1, 1);
        if (s + 2 < NSTEP) CONVWRITE(0, gB, wB);   // col(s+2) -> buf0
        BAR();
    }

#undef ISSUE
#undef CONVWRITE
#undef GEMMSTEP
#undef BAR

    // ---- Epilogue: D(i,j): row = 4*(lane>>4)+r, col = lane&15 --------------
#pragma unroll
    for (int m = 0; m < 2; ++m) {
        const int o_base = (mt0 + m) * 16 + ((lane >> 4) << 2);
#pragma unroll
        for (int r = 0; r < 4; ++r) {
            const int o = o_base + r;
            float* orow = out + (((size_t)(b * CO_ + o) * 64 + ho) * 64 + (woh << 5));
#pragma unroll
            for (int nt = 0; nt < 2; ++nt)
                orow[(nt << 4) | (lane & 15)] = acc[m][nt][r];
        }
    }
}

// ---------------------------------------------------------------------------
extern "C" void kernel_launch(void* const* d_in, const int* in_sizes, int n_in,
                              void* d_out, int out_size, void* d_ws, size_t ws_size,
                              hipStream_t stream) {
    const float* x      = (const float*)d_in[0];
    const float* offset = (const float*)d_in[1];
    const float* weight = (const float*)d_in[2];
    float* out = (float*)d_out;

    const size_t pk_bytes = (size_t)NSTEP * 16 * 64 * 8 * 2;  // 1,179,648 B
    const int use_pk = (ws_size >= pk_bytes) ? 1 : 0;
    unsigned short* wpk = (unsigned short*)d_ws;

    if (use_pk) {
        wpack_kernel<<<288, 256, 0, stream>>>(weight, wpk);
    }
    dcn_mfma_kernel<<<512, 512, 0, stream>>>(x, offset, wpk, weight, out, use_pk);
}

// Round 5
// 96.190 us; speedup vs baseline: 1.4948x; 1.4948x over previous
//
#include <hip/hip_runtime.h>
#include <cstddef>

// Problem constants:
//   x      [4, 256, 64, 64] fp32
//   offset [4, 18, 64, 64]  fp32   (dy,dx) per 3x3 tap
//   weight [256, 256, 3, 3] fp32
//   out    [4, 256, 64, 64] fp32
// stride=1, pad=1, dil=1 -> Ho=Wo=64
#define B_    4
#define C_    256
#define H_    64
#define W_    64
#define CO_   256
#define K2_   9
#define NSTEP 72      // K = 2304 = 72 steps of 32, k-order: k = c*9 + tap

typedef __attribute__((ext_vector_type(8))) short short8;
typedef __attribute__((ext_vector_type(4))) float f32x4;

__device__ __forceinline__ unsigned short f2bf(float f) {
    unsigned int u = __builtin_bit_cast(unsigned int, f);
    u = (u + 0x7fffu + ((u >> 16) & 1u)) >> 16;   // RNE
    return (unsigned short)u;
}

__device__ __forceinline__ unsigned pack2bf(float lo, float hi) {
    return (unsigned)f2bf(lo) | ((unsigned)f2bf(hi) << 16);
}

// ---------------------------------------------------------------------------
// weight [Co][C*9] fp32 (flat k = c*9+tap) -> wpk[s][mt][lane][e] bf16 in MFMA
// A-fragment order. A(i,k): i = lane&15, k = 32s + 8*(lane>>4) + e.
// ---------------------------------------------------------------------------
__global__ void wpack_kernel(const float* __restrict__ w,
                             unsigned short* __restrict__ wpk) {
    const int idx = blockIdx.x * 256 + threadIdx.x;   // 72*16*64 = 73728
    if (idx >= NSTEP * 16 * 64) return;
    const int lane = idx & 63;
    const int mt   = (idx >> 6) & 15;
    const int s    = idx >> 10;
    const int o    = mt * 16 + (lane & 15);
    const int kb   = 32 * s + ((lane >> 4) << 3);
    unsigned short h[8];
#pragma unroll
    for (int e = 0; e < 8; ++e)
        h[e] = f2bf(w[o * 2304 + kb + e]);
    uint4 v;
    v.x = h[0] | ((unsigned)h[1] << 16);
    v.y = h[2] | ((unsigned)h[3] << 16);
    v.z = h[4] | ((unsigned)h[5] << 16);
    v.w = h[6] | ((unsigned)h[7] << 16);
    *reinterpret_cast<uint4*>(&wpk[(size_t)idx * 8]) = v;
}

__device__ __forceinline__ short8 loadA(const unsigned short* __restrict__ wpk,
                                        const float* __restrict__ wraw,
                                        int use_pk, int s, int mt, int lane) {
    if (use_pk) {
        return *reinterpret_cast<const short8*>(
            wpk + (((size_t)(s * 16 + mt) * 64 + lane) << 3));
    } else {
        const int o  = mt * 16 + (lane & 15);
        const int kb = 32 * s + ((lane >> 4) << 3);
        short8 r;
#pragma unroll
        for (int e = 0; e < 8; ++e)
            r[e] = (short)f2bf(wraw[o * 2304 + kb + e]);
        return r;
    }
}

// ---------------------------------------------------------------------------
// Fused deformable conv, bf16 MFMA implicit GEMM with LDS sampling window.
// Block = (b, ho, wo-half): M=256 x N=32, K=2304. Grid 512 -> 2 blocks/CU.
// K-order c-major: chunk cc = channels [32cc,32cc+32) = 9 K-steps; the 10x40
// per-channel bilinear window is staged in LDS once per chunk (tap-invariant).
// ---------------------------------------------------------------------------
__global__ __launch_bounds__(512, 4)
void dcn_mfma_kernel(const float* __restrict__ x,
                     const float* __restrict__ off,
                     const unsigned short* __restrict__ wpk,
                     const float* __restrict__ wraw,
                     float* __restrict__ out,
                     int use_pk) {
    // LDS: window 32ch x 10rows x 40cols (+slack for benign over-reads)
    __shared__ __align__(16) float s_win[32 * 400 + 48];          // 51392 B
    __shared__ __align__(16) float4 s_meta[K2_ * 32];             // 4608 B
    __shared__ int s_base[K2_ * 32];                              // 1152 B
    __shared__ __align__(16) unsigned short s_colb[2][1024];      // 4096 B

    const int tid = threadIdx.x;
    const int bid = blockIdx.x;
    // XCD swizzle: xcd = bid&7 owns (b = xcd>>1, ho band = (xcd&1)*32).
    const int xcd  = bid & 7;
    const int slot = bid >> 3;
    const int b    = xcd >> 1;
    const int ho   = ((xcd & 1) << 5) | (slot >> 1);
    const int woh  = slot & 1;
    const int wo0  = woh << 5;

    const char* xb8 = (const char*)(x + ((size_t)b * C_ * H_ * W_));

    // ---- Phase 1: per-(tap, wo) metadata -----------------------------------
    if (tid < K2_ * 32) {
        const int t = tid >> 5;
        const int p = tid & 31;
        const int pa = wo0 + p;
        const float dy = off[((b * 18 + 2 * t    ) * 64 + ho) * 64 + pa];
        const float dx = off[((b * 18 + 2 * t + 1) * 64 + ho) * 64 + pa];
        const float py = (float)(ho - 1 + t / 3) + dy;
        const float px = (float)(pa - 1 + t % 3) + dx;
        const float y0f = floorf(py);
        const float x0f = floorf(px);
        const float ly = py - y0f, lx = px - x0f;
        const float hy = 1.0f - ly, hx = 1.0f - lx;
        const int y0 = (int)y0f, x0 = (int)x0f;
        const int y1 = y0 + 1,   x1 = x0 + 1;
        const bool vy0 = (y0 >= 0) & (y0 < H_);
        const bool vy1 = (y1 >= 0) & (y1 < H_);
        const bool vx0 = (x0 >= 0) & (x0 < W_);
        const bool vx1 = (x1 >= 0) & (x1 < W_);
        const int yc0 = min(max(y0, 0), H_ - 1);
        const int yc1 = min(max(y1, 0), H_ - 1);
        const int xc0 = min(max(x0, 0), W_ - 1);
        const int xc1 = min(max(x1, 0), W_ - 1);
        float4 wv;
        wv.x = (vy0 && vx0) ? hy * hx : 0.0f;
        wv.y = (vy0 && vx1) ? hy * lx : 0.0f;
        wv.z = (vy1 && vx0) ? ly * hx : 0.0f;
        wv.w = (vy1 && vx1) ? ly * lx : 0.0f;
        s_meta[t * 32 + p] = wv;
        const int r0 = yc0 - (ho - 4), r1 = yc1 - (ho - 4);
        const int j0 = xc0 - (wo0 - 4), j1 = xc1 - (wo0 - 4);
        const int dys = yc1 - yc0, dxs = xc1 - xc0;         // each 0 or 1
        const bool fast = (r0 >= 0) & (r1 <= 9) & (j0 >= 0) & (j1 <= 39);
        int enc;
        if (fast)
            enc = ((r0 * 40 + j0) << 2) | (dys << 1) | dxs;
        else
            enc = (int)(0x80000000u
                        | (unsigned)((((yc0 << 6) + xc0) << 2) | (dys << 1) | dxs));
        s_base[t * 32 + p] = enc;
    }
    __syncthreads();

    const int lane = tid & 63;
    const int wave = tid >> 6;
    const int wo   = lane & 31;                        // block-local wo
    const int kk0  = (wave << 2) | ((lane >> 5) << 1); // thread's atoms kk0, kk0+1
    // col LDS byte offset (same layout as before, verified):
    const unsigned swr = ((unsigned)(wo >> 4) << 10)
                       | ((unsigned)((wo & 15) | ((kk0 >> 3) << 4)) << 4)
                       | ((unsigned)(kk0 & 7) << 1);
    const unsigned brd = (unsigned)lane << 4;

    f32x4 acc[2][2];
#pragma unroll
    for (int m = 0; m < 2; ++m)
#pragma unroll
        for (int nt = 0; nt < 2; ++nt)
            acc[m][nt] = (f32x4)(0.0f);

    // bilinear atom: value for (channel c, tap t) at this thread's wo
#define ATOM(c_, t_, dst) do {                                             \
        const float4 wv_ = s_meta[(t_) * 32 + wo];                         \
        const int m_ = s_base[(t_) * 32 + wo];                             \
        const int dxs_ = m_ & 1, dys_ = (m_ >> 1) & 1;                     \
        float p00_, p01_, p10_, p11_;                                      \
        if (m_ >= 0) {                                                     \
            const float* wr_ = (const float*)((const char*)s_win           \
                + ((c_) & 31) * 1600 + (m_ & 0x7ffffffc));                 \
            const float a0_ = wr_[0], a1_ = wr_[1];                        \
            const float b0_ = wr_[40], b1_ = wr_[41];                      \
            p00_ = a0_; p01_ = dxs_ ? a1_ : a0_;                           \
            const float q0_ = dys_ ? b0_ : a0_;                            \
            const float q1_ = dys_ ? b1_ : a1_;                            \
            p10_ = q0_; p11_ = dxs_ ? q1_ : q0_;                           \
        } else {                                                           \
            const char* pl_ = xb8 + ((size_t)(c_) << 14);                  \
            const int o_ = m_ & 0x7ffffffc;                                \
            p00_ = *(const float*)(pl_ + o_);                              \
            p01_ = *(const float*)(pl_ + o_ + (dxs_ << 2));                \
            p10_ = *(const float*)(pl_ + o_ + (dys_ << 8));                \
            p11_ = *(const float*)(pl_ + o_ + (dys_ << 8) + (dxs_ << 2));  \
        }                                                                  \
        dst = wv_.x * p00_ + wv_.y * p01_ + wv_.z * p10_ + wv_.w * p11_;   \
    } while (0)

    // compute this thread's two col atoms for step sN, write to buf (sN&1)
#define COLSTEP(sN) do {                                                   \
        const int k0_ = 32 * (sN) + kk0;                                   \
        const int c0_ = k0_ / 9;                                           \
        const int t0_ = k0_ - 9 * c0_;                                     \
        int c1_ = c0_, t1_ = t0_ + 1;                                      \
        if (t1_ == 9) { c1_++; t1_ = 0; }                                  \
        float v0_, v1_;                                                    \
        ATOM(c0_, t0_, v0_);                                               \
        ATOM(c1_, t1_, v1_);                                               \
        *(unsigned*)((char*)s_colb[(sN) & 1] + swr) = pack2bf(v0_, v1_);   \
    } while (0)

#define GEMMSTEP(a0, a1, buf) do {                                         \
        short8 b0_ = *(const short8*)((const char*)s_colb[buf] + brd);     \
        short8 b1_ = *(const short8*)((const char*)s_colb[buf] + brd + 1024); \
        acc[0][0] = __builtin_amdgcn_mfma_f32_16x16x32_bf16(a0, b0_, acc[0][0], 0, 0, 0); \
        acc[0][1] = __builtin_amdgcn_mfma_f32_16x16x32_bf16(a0, b1_, acc[0][1], 0, 0, 0); \
        acc[1][0] = __builtin_amdgcn_mfma_f32_16x16x32_bf16(a1, b0_, acc[1][0], 0, 0, 0); \
        acc[1][1] = __builtin_amdgcn_mfma_f32_16x16x32_bf16(a1, b1_, acc[1][1], 0, 0, 0); \
    } while (0)

#define BARLG() do {                                                       \
        asm volatile("s_waitcnt lgkmcnt(0)" ::: "memory");                 \
        __builtin_amdgcn_s_barrier();                                      \
    } while (0)

    const int mt0 = wave << 1;

    // ---- Main loop: 8 chunks x (stage window + 9 K-steps) ------------------
    for (int cc = 0; cc < 8; ++cc) {
        // stage 32 channels' 10x40 windows (coalesced float4)
        const int cbase = cc << 5;
        for (int i = tid; i < 3200; i += 512) {
            const int cl  = i / 100;
            const int rem = i - cl * 100;
            const int r   = rem / 10;
            const int q   = rem - r * 10;
            const int y   = ho - 4 + r;
            if ((unsigned)y < 64u) {
                int gof = (((y << 6) + wo0 - 4) << 2) + (q << 4);
                gof = min(max(gof, 0), 16384 - 16);
                const float4 v = *(const float4*)(
                    xb8 + (((size_t)(cbase + cl)) << 14) + gof);
                *(float4*)((char*)s_win + cl * 1600 + r * 160 + (q << 4)) = v;
            }
        }
        __syncthreads();                 // window visible (vm drain ok here)

        COLSTEP(9 * cc);                 // prologue col for first step of chunk
        BARLG();

        for (int j = 0; j < 9; ++j) {
            const int s = 9 * cc + j;
            const short8 a0 = loadA(wpk, wraw, use_pk, s, mt0, lane);
            const short8 a1 = loadA(wpk, wraw, use_pk, s, mt0 + 1, lane);
            if (j < 8) COLSTEP(s + 1);   // next col while A-loads in flight
            GEMMSTEP(a0, a1, s & 1);
            BARLG();
        }
    }

#undef ATOM
#undef COLSTEP
#undef GEMMSTEP
#undef BARLG

    // ---- Epilogue: D(i,j): row = 4*(lane>>4)+r, col = lane&15 --------------
#pragma unroll
    for (int m = 0; m < 2; ++m) {
        const int o_base = (mt0 + m) * 16 + ((lane >> 4) << 2);
#pragma unroll
        for (int r = 0; r < 4; ++r) {
            const int o = o_base + r;
            float* orow = out + (((size_t)(b * CO_ + o) * 64 + ho) * 64 + wo0);
#pragma unroll
            for (int nt = 0; nt < 2; ++nt)
                orow[(nt << 4) | (lane & 15)] = acc[m][nt][r];
        }
    }
}

// ---------------------------------------------------------------------------
extern "C" void kernel_launch(void* const* d_in, const int* in_sizes, int n_in,
                              void* d_out, int out_size, void* d_ws, size_t ws_size,
                              hipStream_t stream) {
    const float* x      = (const float*)d_in[0];
    const float* offset = (const float*)d_in[1];
    const float* weight = (const float*)d_in[2];
    float* out = (float*)d_out;

    const size_t pk_bytes = (size_t)NSTEP * 16 * 64 * 8 * 2;  // 1,179,648 B
    const int use_pk = (ws_size >= pk_bytes) ? 1 : 0;
    unsigned short* wpk = (unsigned short*)d_ws;

    if (use_pk) {
        wpack_kernel<<<288, 256, 0, stream>>>(weight, wpk);
    }
    dcn_mfma_kernel<<<512, 512, 0, stream>>>(x, offset, wpk, weight, out, use_pk);
}

// Round 6
// 71.259 us; speedup vs baseline: 2.0178x; 1.3499x over previous
//
#include <hip/hip_runtime.h>
#include <hip/hip_bf16.h>
#include <cstddef>

// x [4,256,64,64] f32 | offset [4,18,64,64] f32 | weight [256,256,3,3] f32
// out [4,256,64,64] f32 ; stride=1 pad=1 dil=1 -> Ho=Wo=64
#define B_    4
#define C_    256
#define H_    64
#define W_    64
#define CO_   256
#define K2_   9
#define NSTEP 72   // K = 2304; step s = 9*cc + tap, atoms within step = 32 channels

typedef __attribute__((ext_vector_type(8))) short short8;
typedef __attribute__((ext_vector_type(4))) float f32x4;

__device__ __forceinline__ unsigned short f2bf(float f) {
    unsigned u = __builtin_bit_cast(unsigned, f);
    u = (u + 0x7fffu + ((u >> 16) & 1u)) >> 16;   // RNE
    return (unsigned short)u;
}
__device__ __forceinline__ unsigned pack2bf(float lo, float hi) {
    __hip_bfloat162 h = __float22bfloat162_rn(make_float2(lo, hi));
    unsigned r; __builtin_memcpy(&r, &h, 4);
    return r;
}

// ---------------------------------------------------------------------------
// weight -> wpk[s][mt][lane][e] bf16, MFMA A-frag order with tap-major K:
// step s: cc = s/9, tap = s%9; k-atom kk -> channel c = 32cc + kk.
// A(i,k): i = lane&15 -> o = mt*16+i ; kk = 8*(lane>>4)+e.
// ---------------------------------------------------------------------------
__global__ void wpack_kernel(const float* __restrict__ w,
                             unsigned short* __restrict__ wpk) {
    const int idx = blockIdx.x * 256 + threadIdx.x;   // 72*16*64 = 73728
    if (idx >= NSTEP * 16 * 64) return;
    const int lane = idx & 63;
    const int mt   = (idx >> 6) & 15;
    const int s    = idx >> 10;
    const int o    = mt * 16 + (lane & 15);
    const int cc   = s / 9;
    const int t    = s - 9 * cc;
    const int c0   = cc * 32 + ((lane >> 4) << 3);
    unsigned short h[8];
#pragma unroll
    for (int e = 0; e < 8; ++e)
        h[e] = f2bf(w[(o * C_ + c0 + e) * K2_ + t]);
    uint4 v;
    v.x = h[0] | ((unsigned)h[1] << 16);
    v.y = h[2] | ((unsigned)h[3] << 16);
    v.z = h[4] | ((unsigned)h[5] << 16);
    v.w = h[6] | ((unsigned)h[7] << 16);
    *reinterpret_cast<uint4*>(&wpk[(size_t)idx * 8]) = v;
}

__device__ __forceinline__ short8 loadA(const unsigned short* __restrict__ wpk,
                                        const float* __restrict__ wraw,
                                        int use_pk, int s, int mt, int lane) {
    if (use_pk) {
        return *reinterpret_cast<const short8*>(
            wpk + (((size_t)(s * 16 + mt) * 64 + lane) << 3));
    } else {
        const int cc = s / 9;
        const int t  = s - 9 * cc;
        const int c0 = cc * 32 + ((lane >> 4) << 3);
        const int o  = mt * 16 + (lane & 15);
        short8 r;
#pragma unroll
        for (int e = 0; e < 8; ++e)
            r[e] = (short)f2bf(wraw[(o * C_ + c0 + e) * K2_ + t]);
        return r;
    }
}

// ---------------------------------------------------------------------------
// Block = (b, ho, wo-half): M=256 x N=32, K=2304. Grid 512 -> 2 blocks/CU.
// Per chunk cc: stage 32 channels' 11x48 windows (rows ho-5..ho+5, cols
// wo0-8..wo0+39, 16B-aligned) in LDS; 9 tap-steps of K=32 each.
// ---------------------------------------------------------------------------
__global__ __launch_bounds__(512, 4)
void dcn_mfma_kernel(const float* __restrict__ x,
                     const float* __restrict__ off,
                     const unsigned short* __restrict__ wpk,
                     const float* __restrict__ wraw,
                     float* __restrict__ out,
                     int use_pk) {
    __shared__ __align__(16) float s_win[32 * 528 + 64];          // 67840 B
    __shared__ __align__(16) float s_meta[K2_ * 32 * 4];          // 4608 B (folded wts)
    __shared__ int s_base[K2_ * 32];                               // 1152 B
    __shared__ __align__(16) unsigned short s_colb[2][1024];       // 4096 B

    const int tid = threadIdx.x;
    const int bid = blockIdx.x;
    const int xcd  = bid & 7;
    const int slot = bid >> 3;
    const int b    = xcd >> 1;
    const int ho   = ((xcd & 1) << 5) | (slot >> 1);
    const int woh  = slot & 1;
    const int wo0  = woh << 5;

    const char* xb8 = (const char*)x + ((size_t)b << 22);  // batch plane base

    // ---- Phase 1: per-(tap,wo) folded weights + base encoding --------------
    if (tid < K2_ * 32) {
        const int t = tid >> 5;
        const int p = tid & 31;
        const int pa = wo0 + p;
        const float dy = off[((b * 18 + 2 * t    ) * 64 + ho) * 64 + pa];
        const float dx = off[((b * 18 + 2 * t + 1) * 64 + ho) * 64 + pa];
        const float py = (float)(ho - 1 + t / 3) + dy;
        const float px = (float)(pa - 1 + t % 3) + dx;
        const float y0f = floorf(py), x0f = floorf(px);
        const float ly = py - y0f, lx = px - x0f;
        const float hy = 1.0f - ly, hx = 1.0f - lx;
        const int y0 = (int)y0f, x0 = (int)x0f;
        const int y1 = y0 + 1,   x1 = x0 + 1;
        const bool vy0 = (y0 >= 0) & (y0 < H_);
        const bool vy1 = (y1 >= 0) & (y1 < H_);
        const bool vx0 = (x0 >= 0) & (x0 < W_);
        const bool vx1 = (x1 >= 0) & (x1 < W_);
        const int yc0 = min(max(y0, 0), H_ - 1);
        const int yc1 = min(max(y1, 0), H_ - 1);
        const int xc0 = min(max(x0, 0), W_ - 1);
        const int xc1 = min(max(x1, 0), W_ - 1);
        float w00 = (vy0 && vx0) ? hy * hx : 0.0f;
        float w01 = (vy0 && vx1) ? hy * lx : 0.0f;
        float w10 = (vy1 && vx0) ? ly * hx : 0.0f;
        float w11 = (vy1 && vx1) ? ly * lx : 0.0f;
        const int dys = yc1 - yc0, dxs = xc1 - xc0;   // 0 or 1
        // fold: when duplicate coordinate, merge weight so the extra read
        // (same or garbage cell) carries weight 0.
        if (!dxs) { w00 += w01; w01 = 0.0f; w10 += w11; w11 = 0.0f; }
        if (!dys) { w00 += w10; w10 = 0.0f; w01 += w11; w11 = 0.0f; }
        const int r0 = yc0 - (ho - 5);       // window rows ho-5..ho+5
        const int j0 = xc0 - (wo0 - 8);      // window cols wo0-8..wo0+39
        const bool fast = (r0 >= 0) & (r0 + dys <= 10) & (j0 >= 0) & (j0 + dxs <= 47);
        int enc;
        if (fast)
            enc = (r0 * 48 + j0) << 2;                             // LDS byte off
        else
            enc = (int)(0x80000000u
                        | (unsigned)((((yc0 << 6) + xc0) << 2) | (dys << 1) | dxs));
        float* mp = &s_meta[(t * 32 + p) * 4];
        mp[0] = w00; mp[1] = w01; mp[2] = w10; mp[3] = w11;
        s_base[t * 32 + p] = enc;
    }

    // ---- staging offsets: 132 float4/channel, linear LDS = i*16 ------------
    int goffv[9];
#pragma unroll
    for (int v = 0; v < 9; ++v) {
        const int i   = tid + v * 512;          // cell id (valid < 4224)
        const int cl  = i / 132;
        const int rem = i - cl * 132;
        const int r   = rem / 12;               // 12 float4 per 48-col row
        const int q   = rem - r * 12;
        const int y   = ho - 5 + r;
        int gof = (((y << 6) + wo0 - 8) << 2) + (q << 4);   // 16B aligned
        gof = min(max(gof, 0), 16384 - 16);
        if ((unsigned)y >= 64u) gof = 0;        // OOB row: garbage, never read
        goffv[v] = (cl << 14) + gof;
    }
    __syncthreads();

    const int lane = tid & 63;
    const int wave = tid >> 6;
    const int wo   = lane & 31;
    const int kk0  = (wave << 2) | ((lane >> 5) << 1);  // 2 channels: kk0,kk0+1
    const unsigned swr = ((unsigned)(wo >> 4) << 10)
                       | ((unsigned)((wo & 15) | ((kk0 >> 3) << 4)) << 4)
                       | ((unsigned)(kk0 & 7) << 1);
    const unsigned brd = (unsigned)lane << 4;
    const int mt0 = wave << 1;
    const char* winA = (const char*)s_win + kk0 * 2112;  // 528 floats/ch

    f32x4 acc[2][2];
#pragma unroll
    for (int m = 0; m < 2; ++m)
#pragma unroll
        for (int nt = 0; nt < 2; ++nt)
            acc[m][nt] = (f32x4)(0.0f);

#define COLT(t_, buf_) do {                                                    \
        const float* mp_ = (const float*)((const char*)s_meta                  \
                                          + (t_) * 512 + (wo << 4));           \
        const float w0_ = mp_[0], w1_ = mp_[1], w2_ = mp_[2], w3_ = mp_[3];    \
        const int mb_ = s_base[(t_) * 32 + wo];                                \
        float vA_, vB_;                                                        \
        if (__builtin_expect(mb_ >= 0, 1)) {                                   \
            const float* pA_ = (const float*)(winA + mb_);                     \
            const float* pB_ = (const float*)(winA + 2112 + mb_);              \
            vA_ = w0_*pA_[0] + w1_*pA_[1] + w2_*pA_[48] + w3_*pA_[49];         \
            vB_ = w0_*pB_[0] + w1_*pB_[1] + w2_*pB_[48] + w3_*pB_[49];         \
        } else {                                                               \
            const int dxb_ = (mb_ & 1) << 2, dyb_ = (mb_ & 2) << 7;            \
            const int o_ = mb_ & 0x3fffc;                                      \
            const char* plA_ = xcb + ((size_t)kk0 << 14);                      \
            const char* plB_ = plA_ + (1 << 14);                               \
            vA_ = w0_ * *(const float*)(plA_ + o_)                             \
                + w1_ * *(const float*)(plA_ + o_ + dxb_)                      \
                + w2_ * *(const float*)(plA_ + o_ + dyb_)                      \
                + w3_ * *(const float*)(plA_ + o_ + dyb_ + dxb_);              \
            vB_ = w0_ * *(const float*)(plB_ + o_)                             \
                + w1_ * *(const float*)(plB_ + o_ + dxb_)                      \
                + w2_ * *(const float*)(plB_ + o_ + dyb_)                      \
                + w3_ * *(const float*)(plB_ + o_ + dyb_ + dxb_);              \
        }                                                                      \
        *(unsigned*)((char*)s_colb[buf_] + swr) = pack2bf(vA_, vB_);           \
    } while (0)

#define GEMMSTEP(a0_, a1_, buf_) do {                                          \
        const char* cb_ = (const char*)s_colb[buf_];                           \
        short8 b0_ = *(const short8*)(cb_ + brd);                              \
        short8 b1_ = *(const short8*)(cb_ + brd + 1024);                       \
        acc[0][0] = __builtin_amdgcn_mfma_f32_16x16x32_bf16(a0_, b0_, acc[0][0], 0, 0, 0); \
        acc[0][1] = __builtin_amdgcn_mfma_f32_16x16x32_bf16(a0_, b1_, acc[0][1], 0, 0, 0); \
        acc[1][0] = __builtin_amdgcn_mfma_f32_16x16x32_bf16(a1_, b0_, acc[1][0], 0, 0, 0); \
        acc[1][1] = __builtin_amdgcn_mfma_f32_16x16x32_bf16(a1_, b1_, acc[1][1], 0, 0, 0); \
    } while (0)

#define BARLG() do {                                                           \
        asm volatile("s_waitcnt lgkmcnt(0)" ::: "memory");                     \
        __builtin_amdgcn_s_barrier();                                          \
    } while (0)

    short8 a0 = loadA(wpk, wraw, use_pk, 0, mt0, lane);
    short8 a1 = loadA(wpk, wraw, use_pk, 0, mt0 + 1, lane);

    for (int cc = 0; cc < 8; ++cc) {
        const char* xcb = xb8 + ((size_t)cc << 19);   // 32 planes = 512 KB
        // ---- stage window: 8 full slots + 1 tail (2 waves) -----------------
        {
            char* wbase = (char*)s_win + (size_t)tid * 16;
            float4 s0 = *(const float4*)(xcb + goffv[0]);
            float4 s1 = *(const float4*)(xcb + goffv[1]);
            float4 s2 = *(const float4*)(xcb + goffv[2]);
            float4 s3 = *(const float4*)(xcb + goffv[3]);
            *(float4*)(wbase +     0) = s0;
            *(float4*)(wbase +  8192) = s1;
            *(float4*)(wbase + 16384) = s2;
            *(float4*)(wbase + 24576) = s3;
            float4 s4 = *(const float4*)(xcb + goffv[4]);
            float4 s5 = *(const float4*)(xcb + goffv[5]);
            float4 s6 = *(const float4*)(xcb + goffv[6]);
            float4 s7 = *(const float4*)(xcb + goffv[7]);
            *(float4*)(wbase + 32768) = s4;
            *(float4*)(wbase + 40960) = s5;
            *(float4*)(wbase + 49152) = s6;
            *(float4*)(wbase + 57344) = s7;
            if (tid < 128) {
                float4 s8 = *(const float4*)(xcb + goffv[8]);
                *(float4*)(wbase + 65536) = s8;
            }
        }
        __syncthreads();

        COLT(0, 0);
        BARLG();

#pragma unroll
        for (int j = 0; j < 9; ++j) {
            const int sj = cc * 9 + j;
            short8 n0, n1;
            const bool pf = (sj + 1 < NSTEP);
            if (pf) {
                n0 = loadA(wpk, wraw, use_pk, sj + 1, mt0, lane);
                n1 = loadA(wpk, wraw, use_pk, sj + 1, mt0 + 1, lane);
            }
            if (j < 8) COLT(j + 1, (j + 1) & 1);
            GEMMSTEP(a0, a1, j & 1);
            BARLG();
            if (pf) { a0 = n0; a1 = n1; }
        }
    }

#undef COLT
#undef GEMMSTEP
#undef BARLG

    // ---- Epilogue: D(i,j): row = 4*(lane>>4)+r, col = lane&15 --------------
#pragma unroll
    for (int m = 0; m < 2; ++m) {
        const int ob = (mt0 + m) * 16 + ((lane >> 4) << 2);
#pragma unroll
        for (int r = 0; r < 4; ++r) {
            float* orow = out + (((size_t)(b * CO_ + ob + r) * 64 + ho) * 64 + wo0);
#pragma unroll
            for (int nt = 0; nt < 2; ++nt)
                orow[(nt << 4) | (lane & 15)] = acc[m][nt][r];
        }
    }
}

// ---------------------------------------------------------------------------
extern "C" void kernel_launch(void* const* d_in, const int* in_sizes, int n_in,
                              void* d_out, int out_size, void* d_ws, size_t ws_size,
                              hipStream_t stream) {
    const float* x      = (const float*)d_in[0];
    const float* offset = (const float*)d_in[1];
    const float* weight = (const float*)d_in[2];
    float* out = (float*)d_out;

    const size_t pk_bytes = (size_t)NSTEP * 16 * 64 * 8 * 2;  // 1,179,648 B
    const int use_pk = (ws_size >= pk_bytes) ? 1 : 0;
    unsigned short* wpk = (unsigned short*)d_ws;

    if (use_pk) {
        wpack_kernel<<<288, 256, 0, stream>>>(weight, wpk);
    }
    dcn_mfma_kernel<<<512, 512, 0, stream>>>(x, offset, wpk, weight, out, use_pk);
}